// Round 1
// baseline (294.512 us; speedup 1.0000x reference)
//
#include <hip/hip_runtime.h>
#include <stdint.h>
#include <stddef.h>

// ---------- types ----------
typedef __attribute__((ext_vector_type(8))) short bf16x8;   // 8 bf16 = 4 VGPRs
typedef __attribute__((ext_vector_type(4))) short short4v;
typedef __attribute__((ext_vector_type(4))) float f32x4;

// bf16 round-to-nearest-even from fp32
__device__ __forceinline__ short f2bf(float f) {
  union { float f; uint32_t u; } x; x.f = f;
  return (short)((x.u + 0x7fffu + ((x.u >> 16) & 1u)) >> 16);
}

// async global->LDS, 16B per lane; lds base must be wave-uniform
__device__ __forceinline__ void gload_lds16(const void* g, void* lds) {
  __builtin_amdgcn_global_load_lds(
      (const __attribute__((address_space(1))) void*)g,
      (__attribute__((address_space(3))) void*)lds, 16, 0, 0);
}

// ---------- elementwise casts ----------
__global__ __launch_bounds__(256) void cast_b(const float* __restrict__ s,
                                              short* __restrict__ d) {
  int i4 = (blockIdx.x * 256 + threadIdx.x) * 4;
  float4 v = *(const float4*)&s[i4];
  short4v r = { f2bf(v.x), f2bf(v.y), f2bf(v.z), f2bf(v.w) };
  *(short4v*)&d[i4] = r;
}

__global__ __launch_bounds__(256) void cast_add(const float* __restrict__ a,
                                                const float* __restrict__ b,
                                                short* __restrict__ o) {
  int i4 = (blockIdx.x * 256 + threadIdx.x) * 4;
  float4 va = *(const float4*)&a[i4];
  float4 vb = *(const float4*)&b[i4];
  short4v r = { f2bf(va.x + vb.x), f2bf(va.y + vb.y),
                f2bf(va.z + vb.z), f2bf(va.w + vb.w) };
  *(short4v*)&o[i4] = r;
}

// transpose-cast weights: W [1024 k][1024 n] fp32 -> WT [n][k] bf16
__global__ __launch_bounds__(256) void transW(const float* __restrict__ Wq,
                                              const float* __restrict__ Wk,
                                              const float* __restrict__ Wv,
                                              const float* __restrict__ Wo,
                                              short* __restrict__ WcatT,
                                              short* __restrict__ WoT) {
  int z = blockIdx.z;
  const float* src = (z == 0) ? Wq : (z == 1) ? Wk : (z == 2) ? Wv : Wo;
  short* dst = (z == 3) ? WoT : WcatT + (size_t)z * 1024 * 1024;
  __shared__ float tl[32][33];
  int tx = threadIdx.x & 31, ty = threadIdx.x >> 5;  // 32 x 8
  int kk0 = blockIdx.x * 32;   // src rows (k)
  int nn0 = blockIdx.y * 32;   // src cols (n)
#pragma unroll
  for (int j = 0; j < 4; j++)
    tl[ty + j * 8][tx] = src[(size_t)(kk0 + ty + j * 8) * 1024 + nn0 + tx];
  __syncthreads();
#pragma unroll
  for (int j = 0; j < 4; j++)
    dst[(size_t)(nn0 + ty + j * 8) * 1024 + kk0 + tx] = f2bf(tl[tx][ty + j * 8]);
}

// V [h][k 2048][d 64] -> Vt [h][d 64][k 2048]
__global__ __launch_bounds__(256) void transpose_v(const short* __restrict__ Vb,
                                                   short* __restrict__ Vt) {
  __shared__ short tv[64][72];
  int h = blockIdx.y, k0 = blockIdx.x * 64;
  int tid = threadIdx.x;
#pragma unroll
  for (int j = 0; j < 2; j++) {
    int idx = tid + j * 256;
    int row = idx >> 3, c = idx & 7;
    bf16x8 v = *(const bf16x8*)&Vb[((size_t)h * 2048 + k0 + row) * 64 + c * 8];
#pragma unroll
    for (int t = 0; t < 8; t++) tv[row][c * 8 + t] = v[t];
  }
  __syncthreads();
#pragma unroll
  for (int j = 0; j < 2; j++) {
    int idx = tid + j * 256;
    int d = idx >> 3, c = idx & 7;
    bf16x8 v;
#pragma unroll
    for (int t = 0; t < 8; t++) v[t] = tv[c * 8 + t][d];
    *(bf16x8*)&Vt[((size_t)h * 64 + d) * 2048 + k0 + c * 8] = v;
  }
}

// ---------- MFMA GEMM: C[MxN] = A[MxK] * B^T where B stored [N][K] ----------
// MODE 0: plain fp32 store to C.  MODE 1: QKV epilogue (RoPE on Q,K; bf16 split-head stores)
template <int MODE>
__global__ __launch_bounds__(256, 2)
void gemm_kernel(const short* __restrict__ A, const short* __restrict__ B,
                 int N, int K, float* __restrict__ C,
                 short* __restrict__ Qb, short* __restrict__ Kb,
                 short* __restrict__ Vb) {
  __shared__ __attribute__((aligned(16))) short lga[128 * 64];
  __shared__ __attribute__((aligned(16))) short lgb[128 * 64];
  const int tid = threadIdx.x;
  const int lane = tid & 63;
  const int w = tid >> 6;
  const int l15 = lane & 15;
  const int quad = lane >> 4;
  const int wm = w >> 1, wn = w & 1;
  const int m0 = blockIdx.x * 128, n0 = blockIdx.y * 128;
  const int rsub = lane >> 3;   // 0..7 (row within 8-row staging chunk)
  const int cpos = lane & 7;    // 16B chunk position within row

  f32x4 acc[4][4];
#pragma unroll
  for (int i = 0; i < 4; i++)
#pragma unroll
    for (int j = 0; j < 4; j++) acc[i][j] = (f32x4){0.f, 0.f, 0.f, 0.f};

  for (int kb = 0; kb < K; kb += 64) {
    __syncthreads();
    // stage 128x64 bf16 A-tile and B-tile, XOR-swizzled chunks (conflict-free frag reads)
#pragma unroll
    for (int j = 0; j < 4; j++) {
      int r = (w * 4 + j) * 8 + rsub;       // 0..127
      int kc = cpos ^ rsub;                 // logical chunk = pos ^ (row&7); base rows %8==0
      gload_lds16(A + (size_t)(m0 + r) * K + kb + kc * 8, &lga[(w * 4 + j) * 512]);
      gload_lds16(B + (size_t)(n0 + r) * K + kb + kc * 8, &lgb[(w * 4 + j) * 512]);
    }
    __syncthreads();
#pragma unroll
    for (int kk = 0; kk < 2; kk++) {
      bf16x8 af[4], bfr[4];
#pragma unroll
      for (int t = 0; t < 4; t++) {
        int row = wm * 64 + t * 16 + l15;
        int pc = (kk * 4 + quad) ^ (row & 7);
        af[t] = *(const bf16x8*)&lga[row * 64 + pc * 8];
        int rowb = wn * 64 + t * 16 + l15;
        int pcb = (kk * 4 + quad) ^ (rowb & 7);
        bfr[t] = *(const bf16x8*)&lgb[rowb * 64 + pcb * 8];
      }
#pragma unroll
      for (int mt = 0; mt < 4; mt++)
#pragma unroll
        for (int nt = 0; nt < 4; nt++)
          acc[mt][nt] = __builtin_amdgcn_mfma_f32_16x16x32_bf16(
              af[mt], bfr[nt], acc[mt][nt], 0, 0, 0);
    }
  }

  if (MODE == 0) {
#pragma unroll
    for (int mt = 0; mt < 4; mt++) {
      int q = m0 + wm * 64 + mt * 16 + quad * 4;
#pragma unroll
      for (int nt = 0; nt < 4; nt++) {
        int n = n0 + wn * 64 + nt * 16 + l15;
#pragma unroll
        for (int r = 0; r < 4; r++) C[(size_t)(q + r) * N + n] = acc[mt][nt][r];
      }
    }
  } else {
    // QKV epilogue. col n: [0,1024)=Q, [1024,2048)=K, [2048,3072)=V; h=(n>>6)&15, d=n&63
#pragma unroll
    for (int mt = 0; mt < 4; mt++) {
#pragma unroll
      for (int nt = 0; nt < 4; nt++) {
        int n = n0 + wn * 64 + nt * 16 + l15;
        int mat = n >> 10;
        int h = (n >> 6) & 15;
        int d = n & 63;
#pragma unroll
        for (int r = 0; r < 4; r++) {
          int q = m0 + wm * 64 + mt * 16 + quad * 4 + r;
          float v = acc[mt][nt][r];
          float o = __shfl_xor(v, 1, 64);  // partner holds d^1 (adjacent lane)
          if (mat < 2) {
            int i = d >> 1;
            // inv_freq = 500^(-i/32); log2(500)/32 = 0.28018075889569...
            float ang = (float)q * __builtin_exp2f(-(float)i * 0.2801807588956902f);
            float sn, cs;
            __sincosf(ang, &sn, &cs);
            float rv = (d & 1) ? (o * sn + v * cs) : (v * cs - o * sn);
            short* dst = (mat == 0) ? Qb : Kb;
            dst[((size_t)h * 2048 + q) * 64 + d] = f2bf(rv);
          } else {
            Vb[((size_t)h * 2048 + q) * 64 + d] = f2bf(v);
          }
        }
      }
    }
  }
}

// ---------- fused attention with head-axis softmax ----------
// grid 256: qt = bid&127 (16 q rows), ks = bid>>7 (k half). 4 waves x 4 heads.
__global__ __launch_bounds__(256, 2)
void attn_kernel(const short* __restrict__ Qb, const short* __restrict__ Kb,
                 const short* __restrict__ Vt, float* __restrict__ Y0,
                 float* __restrict__ Y1) {
  __shared__ float slds[16 * 16 * 33];                              // [h][q][33]
  __shared__ __attribute__((aligned(16))) short alds[16 * 16 * 40]; // [h][q][40]
  const int tid = threadIdx.x;
  const int lane = tid & 63;
  const int w = tid >> 6;
  const int l15 = lane & 15, quad = lane >> 4;
  const int qt = blockIdx.x & 127;
  const int ks = blockIdx.x >> 7;
  const int q0 = qt * 16;
  float* Y = ks ? Y1 : Y0;

  // persistent Q fragments: 4 heads x 2 d-chunks
  bf16x8 qf[4][2];
#pragma unroll
  for (int hh = 0; hh < 4; hh++) {
    int h = w * 4 + hh;
#pragma unroll
    for (int c = 0; c < 2; c++)
      qf[hh][c] = *(const bf16x8*)&Qb[((size_t)h * 2048 + q0 + l15) * 64 + c * 32 + quad * 8];
  }

  f32x4 yacc[4][4];
#pragma unroll
  for (int i = 0; i < 4; i++)
#pragma unroll
    for (int j = 0; j < 4; j++) yacc[i][j] = (f32x4){0.f, 0.f, 0.f, 0.f};

  for (int kt = 0; kt < 32; kt++) {
    int k0 = ks * 1024 + kt * 32;
    // ---- S = Q K^T for this wave's 4 heads (16q x 32k each) ----
#pragma unroll
    for (int hh = 0; hh < 4; hh++) {
      int h = w * 4 + hh;
#pragma unroll
      for (int s = 0; s < 2; s++) {
        const short* kbase = &Kb[((size_t)h * 2048 + k0 + s * 16 + l15) * 64 + quad * 8];
        bf16x8 kf0 = *(const bf16x8*)kbase;
        bf16x8 kf1 = *(const bf16x8*)(kbase + 32);
        f32x4 sa = (f32x4){0.f, 0.f, 0.f, 0.f};
        sa = __builtin_amdgcn_mfma_f32_16x16x32_bf16(qf[hh][0], kf0, sa, 0, 0, 0);
        sa = __builtin_amdgcn_mfma_f32_16x16x32_bf16(qf[hh][1], kf1, sa, 0, 0, 0);
#pragma unroll
        for (int r = 0; r < 4; r++)
          slds[(h * 16 + quad * 4 + r) * 33 + s * 16 + l15] = sa[r];
      }
    }
    __syncthreads();
    // ---- softmax over the 16 heads at each (q,k); masked -> 1/16 ----
#pragma unroll
    for (int pp = 0; pp < 2; pp++) {
      int p = tid + pp * 256;
      int q = p >> 5, kl = p & 31;
      int kg = k0 + kl, qg = q0 + q;
      if (kg > qg) {
#pragma unroll
        for (int h = 0; h < 16; h++)
          alds[(h * 16 + q) * 40 + kl] = (short)0x3D80;  // bf16(0.0625)
      } else {
        float t[16];
        float m = -1e30f;
#pragma unroll
        for (int h = 0; h < 16; h++) {
          t[h] = 0.125f * slds[(h * 16 + q) * 33 + kl];
          m = fmaxf(m, t[h]);
        }
        float sum = 0.f;
#pragma unroll
        for (int h = 0; h < 16; h++) {
          float e = __expf(t[h] - m);
          t[h] = e;
          sum += e;
        }
        float rs = 1.f / sum;
#pragma unroll
        for (int h = 0; h < 16; h++)
          alds[(h * 16 + q) * 40 + kl] = f2bf(t[h] * rs);
      }
    }
    __syncthreads();
    // ---- Y += A @ V ----
#pragma unroll
    for (int hh = 0; hh < 4; hh++) {
      int h = w * 4 + hh;
      bf16x8 af = *(const bf16x8*)&alds[(h * 16 + l15) * 40 + quad * 8];
#pragma unroll
      for (int nt = 0; nt < 4; nt++) {
        bf16x8 vf = *(const bf16x8*)&Vt[((size_t)h * 64 + nt * 16 + l15) * 2048 + k0 + quad * 8];
        yacc[hh][nt] = __builtin_amdgcn_mfma_f32_16x16x32_bf16(af, vf, yacc[hh][nt], 0, 0, 0);
      }
    }
  }
  // store Y partial [q][h*64+d] fp32
#pragma unroll
  for (int hh = 0; hh < 4; hh++) {
    int h = w * 4 + hh;
#pragma unroll
    for (int nt = 0; nt < 4; nt++) {
      int col = h * 64 + nt * 16 + l15;
#pragma unroll
      for (int r = 0; r < 4; r++) {
        int q = q0 + quad * 4 + r;
        Y[(size_t)q * 1024 + col] = yacc[hh][nt][r];
      }
    }
  }
}

// ---------- host ----------
extern "C" void kernel_launch(void* const* d_in, const int* in_sizes, int n_in,
                              void* d_out, int out_size, void* d_ws, size_t ws_size,
                              hipStream_t stream) {
  (void)in_sizes; (void)n_in; (void)out_size; (void)ws_size;
  const float* X  = (const float*)d_in[0];
  // d_in[1] = mask (tril) — causal is hardcoded
  const float* Wq = (const float*)d_in[2];
  const float* Wk = (const float*)d_in[3];
  const float* Wv = (const float*)d_in[4];
  const float* Wo = (const float*)d_in[5];
  char* ws = (char*)d_ws;
  const size_t MB = 1024 * 1024;
  short* Xbf   = (short*)(ws + 0);        // 4 MB
  short* WcatT = (short*)(ws + 4 * MB);   // 6 MB [3072 n][1024 k]
  short* WoT   = (short*)(ws + 10 * MB);  // 2 MB [1024 n][1024 k]
  short* Qb    = (short*)(ws + 12 * MB);  // 4 MB [h][q][64]
  short* Kb    = (short*)(ws + 16 * MB);  // 4 MB [h][k][64]
  short* Vb    = (short*)(ws + 20 * MB);  // 4 MB [h][k][64]
  short* Vt    = (short*)(ws + 24 * MB);  // 4 MB [h][d][2048]
  float* Y0    = (float*)(ws + 28 * MB);  // 8 MB [q][1024]
  float* Y1    = (float*)(ws + 36 * MB);  // 8 MB
  short* Ycbf  = (short*)(ws + 44 * MB);  // 4 MB
  float* out   = (float*)d_out;

  cast_b<<<dim3(2048), dim3(256), 0, stream>>>(X, Xbf);
  transW<<<dim3(32, 32, 4), dim3(256), 0, stream>>>(Wq, Wk, Wv, Wo, WcatT, WoT);
  gemm_kernel<1><<<dim3(16, 24), dim3(256), 0, stream>>>(Xbf, WcatT, 3072, 1024,
                                                         nullptr, Qb, Kb, Vb);
  transpose_v<<<dim3(32, 16), dim3(256), 0, stream>>>(Vb, Vt);
  attn_kernel<<<dim3(256), dim3(256), 0, stream>>>(Qb, Kb, Vt, Y0, Y1);
  cast_add<<<dim3(2048), dim3(256), 0, stream>>>(Y0, Y1, Ycbf);
  gemm_kernel<0><<<dim3(16, 8), dim3(256), 0, stream>>>(Ycbf, WoT, 1024, 1024,
                                                        out, nullptr, nullptr, nullptr);
}

// Round 2
// 235.445 us; speedup vs baseline: 1.2509x; 1.2509x over previous
//
#include <hip/hip_runtime.h>
#include <stdint.h>
#include <stddef.h>

// ---------- types ----------
typedef __attribute__((ext_vector_type(8))) short bf16x8;   // 8 bf16 = 4 VGPRs
typedef __attribute__((ext_vector_type(4))) short short4v;
typedef __attribute__((ext_vector_type(4))) float f32x4;

// bf16 round-to-nearest-even from fp32
__device__ __forceinline__ short f2bf(float f) {
  union { float f; uint32_t u; } x; x.f = f;
  return (short)((x.u + 0x7fffu + ((x.u >> 16) & 1u)) >> 16);
}
__device__ __forceinline__ float bf2f(short s) {
  union { uint32_t u; float f; } x; x.u = ((uint32_t)(uint16_t)s) << 16;
  return x.f;
}

// async global->LDS, 16B per lane; lds base must be wave-uniform
__device__ __forceinline__ void gload_lds16(const void* g, void* lds) {
  __builtin_amdgcn_global_load_lds(
      (const __attribute__((address_space(1))) void*)g,
      (__attribute__((address_space(3))) void*)lds, 16, 0, 0);
}

// ---------- elementwise casts ----------
__global__ __launch_bounds__(256) void cast_b(const float* __restrict__ s,
                                              short* __restrict__ d) {
  int i4 = (blockIdx.x * 256 + threadIdx.x) * 4;
  float4 v = *(const float4*)&s[i4];
  short4v r = { f2bf(v.x), f2bf(v.y), f2bf(v.z), f2bf(v.w) };
  *(short4v*)&d[i4] = r;
}

// out[i] = bf16( sum_s Yp_s[i] + Cvs[i % 1024] )
__global__ __launch_bounds__(256) void cast_add4(const short* __restrict__ Y0,
                                                 const short* __restrict__ Y1,
                                                 const short* __restrict__ Y2,
                                                 const short* __restrict__ Y3,
                                                 const float* __restrict__ Cvs,
                                                 short* __restrict__ o) {
  int i4 = (blockIdx.x * 256 + threadIdx.x) * 4;
  short4v a = *(const short4v*)&Y0[i4];
  short4v b = *(const short4v*)&Y1[i4];
  short4v c = *(const short4v*)&Y2[i4];
  short4v d = *(const short4v*)&Y3[i4];
  short4v r;
#pragma unroll
  for (int j = 0; j < 4; j++) {
    float s = bf2f(a[j]) + bf2f(b[j]) + bf2f(c[j]) + bf2f(d[j]) +
              Cvs[(i4 + j) & 1023];
    r[j] = f2bf(s);
  }
  *(short4v*)&o[i4] = r;
}

// transpose-cast weights: W [1024 k][1024 n] fp32 -> WT [n][k] bf16
__global__ __launch_bounds__(256) void transW(const float* __restrict__ Wq,
                                              const float* __restrict__ Wk,
                                              const float* __restrict__ Wv,
                                              const float* __restrict__ Wo,
                                              short* __restrict__ WcatT,
                                              short* __restrict__ WoT) {
  int z = blockIdx.z;
  const float* src = (z == 0) ? Wq : (z == 1) ? Wk : (z == 2) ? Wv : Wo;
  short* dst = (z == 3) ? WoT : WcatT + (size_t)z * 1024 * 1024;
  __shared__ float tl[32][33];
  int tx = threadIdx.x & 31, ty = threadIdx.x >> 5;  // 32 x 8
  int kk0 = blockIdx.x * 32;   // src rows (k)
  int nn0 = blockIdx.y * 32;   // src cols (n)
#pragma unroll
  for (int j = 0; j < 4; j++)
    tl[ty + j * 8][tx] = src[(size_t)(kk0 + ty + j * 8) * 1024 + nn0 + tx];
  __syncthreads();
#pragma unroll
  for (int j = 0; j < 4; j++)
    dst[(size_t)(nn0 + ty + j * 8) * 1024 + kk0 + tx] = f2bf(tl[tx][ty + j * 8]);
}

// V [h][k 2048][d 64] -> Vt [h][d 64][k 2048]
__global__ __launch_bounds__(256) void transpose_v(const short* __restrict__ Vb,
                                                   short* __restrict__ Vt) {
  __shared__ short tv[64][72];
  int h = blockIdx.y, k0 = blockIdx.x * 64;
  int tid = threadIdx.x;
#pragma unroll
  for (int j = 0; j < 2; j++) {
    int idx = tid + j * 256;
    int row = idx >> 3, c = idx & 7;
    bf16x8 v = *(const bf16x8*)&Vb[((size_t)h * 2048 + k0 + row) * 64 + c * 8];
#pragma unroll
    for (int t = 0; t < 8; t++) tv[row][c * 8 + t] = v[t];
  }
  __syncthreads();
#pragma unroll
  for (int j = 0; j < 2; j++) {
    int idx = tid + j * 256;
    int d = idx >> 3, c = idx & 7;
    bf16x8 v;
#pragma unroll
    for (int t = 0; t < 8; t++) v[t] = tv[c * 8 + t][d];
    *(bf16x8*)&Vt[((size_t)h * 64 + d) * 2048 + k0 + c * 8] = v;
  }
}

// Cvs[h*64+d] = (1/16) * sum_k V[h][k][d]
__global__ __launch_bounds__(256) void vsum(const short* __restrict__ Vb,
                                            float* __restrict__ Cvs) {
  __shared__ float red[16][17];
  int h = blockIdx.x >> 2, dq = blockIdx.x & 3;
  int dl = threadIdx.x & 15, ks = threadIdx.x >> 4;
  int d = dq * 16 + dl;
  float acc = 0.f;
  const short* base = &Vb[((size_t)h * 2048 + ks * 128) * 64 + d];
#pragma unroll 8
  for (int k = 0; k < 128; k++) acc += bf2f(base[(size_t)k * 64]);
  red[dl][ks] = acc;
  __syncthreads();
  if (threadIdx.x < 16) {
    float sum = 0.f;
#pragma unroll
    for (int i = 0; i < 16; i++) sum += red[threadIdx.x][i];
    Cvs[h * 64 + dq * 16 + threadIdx.x] = sum * 0.0625f;
  }
}

// ---------- MFMA GEMM: C[MxN] = A[MxK] * B^T where B stored [N][K] ----------
template <int MODE>
__global__ __launch_bounds__(256, 2)
void gemm_kernel(const short* __restrict__ A, const short* __restrict__ B,
                 int N, int K, float* __restrict__ C,
                 short* __restrict__ Qb, short* __restrict__ Kb,
                 short* __restrict__ Vb) {
  __shared__ __attribute__((aligned(16))) short lga[128 * 64];
  __shared__ __attribute__((aligned(16))) short lgb[128 * 64];
  const int tid = threadIdx.x;
  const int lane = tid & 63;
  const int w = tid >> 6;
  const int l15 = lane & 15;
  const int quad = lane >> 4;
  const int wm = w >> 1, wn = w & 1;
  const int m0 = blockIdx.x * 128, n0 = blockIdx.y * 128;
  const int rsub = lane >> 3;
  const int cpos = lane & 7;

  f32x4 acc[4][4];
#pragma unroll
  for (int i = 0; i < 4; i++)
#pragma unroll
    for (int j = 0; j < 4; j++) acc[i][j] = (f32x4){0.f, 0.f, 0.f, 0.f};

  for (int kb = 0; kb < K; kb += 64) {
    __syncthreads();
#pragma unroll
    for (int j = 0; j < 4; j++) {
      int r = (w * 4 + j) * 8 + rsub;
      int kc = cpos ^ rsub;
      gload_lds16(A + (size_t)(m0 + r) * K + kb + kc * 8, &lga[(w * 4 + j) * 512]);
      gload_lds16(B + (size_t)(n0 + r) * K + kb + kc * 8, &lgb[(w * 4 + j) * 512]);
    }
    __syncthreads();
#pragma unroll
    for (int kk = 0; kk < 2; kk++) {
      bf16x8 af[4], bfr[4];
#pragma unroll
      for (int t = 0; t < 4; t++) {
        int row = wm * 64 + t * 16 + l15;
        int pc = (kk * 4 + quad) ^ (row & 7);
        af[t] = *(const bf16x8*)&lga[row * 64 + pc * 8];
        int rowb = wn * 64 + t * 16 + l15;
        int pcb = (kk * 4 + quad) ^ (rowb & 7);
        bfr[t] = *(const bf16x8*)&lgb[rowb * 64 + pcb * 8];
      }
#pragma unroll
      for (int mt = 0; mt < 4; mt++)
#pragma unroll
        for (int nt = 0; nt < 4; nt++)
          acc[mt][nt] = __builtin_amdgcn_mfma_f32_16x16x32_bf16(
              af[mt], bfr[nt], acc[mt][nt], 0, 0, 0);
    }
  }

  if (MODE == 0) {
#pragma unroll
    for (int mt = 0; mt < 4; mt++) {
      int q = m0 + wm * 64 + mt * 16 + quad * 4;
#pragma unroll
      for (int nt = 0; nt < 4; nt++) {
        int n = n0 + wn * 64 + nt * 16 + l15;
#pragma unroll
        for (int r = 0; r < 4; r++) C[(size_t)(q + r) * N + n] = acc[mt][nt][r];
      }
    }
  } else {
#pragma unroll
    for (int mt = 0; mt < 4; mt++) {
#pragma unroll
      for (int nt = 0; nt < 4; nt++) {
        int n = n0 + wn * 64 + nt * 16 + l15;
        int mat = n >> 10;
        int h = (n >> 6) & 15;
        int d = n & 63;
#pragma unroll
        for (int r = 0; r < 4; r++) {
          int q = m0 + wm * 64 + mt * 16 + quad * 4 + r;
          float v = acc[mt][nt][r];
          float o = __shfl_xor(v, 1, 64);
          if (mat < 2) {
            int i = d >> 1;
            float ang = (float)q * __builtin_exp2f(-(float)i * 0.2801807588956902f);
            float sn, cs;
            __sincosf(ang, &sn, &cs);
            float rv = (d & 1) ? (o * sn + v * cs) : (v * cs - o * sn);
            short* dst = (mat == 0) ? Qb : Kb;
            dst[((size_t)h * 2048 + q) * 64 + d] = f2bf(rv);
          } else {
            Vb[((size_t)h * 2048 + q) * 64 + d] = f2bf(v);
          }
        }
      }
    }
  }
}

// ---------- causal attention, head-axis softmax, A' = A - 1/16 ----------
// grid 512: qt = 127-(bx>>2), split s = bx&3 takes k-groups g = s, s+4, ...
// block 512 thr = 8 waves x 2 heads. Yp: 4 bf16 buffers [2048][1024].
__global__ __launch_bounds__(512, 4)
void attn_kernel(const short* __restrict__ Qb, const short* __restrict__ Kb,
                 const short* __restrict__ Vt, short* __restrict__ Yp) {
  __shared__ short Sb[16 * 16 * 72];
  __shared__ short Ab[16 * 16 * 72];
  const int tid = threadIdx.x;
  const int lane = tid & 63;
  const int w = tid >> 6;                    // 0..7
  const int l15 = lane & 15, quad = lane >> 4;
  const int bx = blockIdx.x;
  const int qt = 127 - (bx >> 2);
  const int s = bx & 3;
  const int q0 = qt * 16;
  const int G = (qt + 4) >> 2;               // ceil((qt+1)/4) 64-wide k-groups
  const int h0 = w * 2;

  bf16x8 qf[2][2];
#pragma unroll
  for (int hh = 0; hh < 2; hh++)
#pragma unroll
    for (int c = 0; c < 2; c++)
      qf[hh][c] = *(const bf16x8*)&Qb[((size_t)(h0 + hh) * 2048 + q0 + l15) * 64 +
                                      c * 32 + quad * 8];

  f32x4 yacc[2][4];
#pragma unroll
  for (int i = 0; i < 2; i++)
#pragma unroll
    for (int j = 0; j < 4; j++) yacc[i][j] = (f32x4){0.f, 0.f, 0.f, 0.f};

  for (int g = s; g < G; g += 4) {
    const int k0 = g * 64;
    // ---- S = (QK^T)/8 -> bf16 LDS [h][q][72] ----
#pragma unroll
    for (int hh = 0; hh < 2; hh++) {
      int h = h0 + hh;
#pragma unroll
      for (int st = 0; st < 4; st++) {
        const short* kb = &Kb[((size_t)h * 2048 + k0 + st * 16 + l15) * 64 + quad * 8];
        bf16x8 kf0 = *(const bf16x8*)kb;
        bf16x8 kf1 = *(const bf16x8*)(kb + 32);
        f32x4 sa = (f32x4){0.f, 0.f, 0.f, 0.f};
        sa = __builtin_amdgcn_mfma_f32_16x16x32_bf16(qf[hh][0], kf0, sa, 0, 0, 0);
        sa = __builtin_amdgcn_mfma_f32_16x16x32_bf16(qf[hh][1], kf1, sa, 0, 0, 0);
#pragma unroll
        for (int r = 0; r < 4; r++)
          Sb[(h * 16 + quad * 4 + r) * 72 + st * 16 + l15] = f2bf(0.125f * sa[r]);
      }
    }
    __syncthreads();
    // ---- head-axis softmax; A' = softmax - 1/16; masked -> 0 ----
#pragma unroll
    for (int pp = 0; pp < 2; pp++) {
      int p = tid + pp * 512;
      int q = p >> 6, kl = p & 63;
      int base = q * 72 + kl;
      float t[16];
      float m = -1e30f;
#pragma unroll
      for (int h = 0; h < 16; h++) {
        t[h] = bf2f(Sb[h * 1152 + base]);
        m = fmaxf(m, t[h]);
      }
      float sum = 0.f;
#pragma unroll
      for (int h = 0; h < 16; h++) {
        float e = __expf(t[h] - m);
        t[h] = e;
        sum += e;
      }
      float rs = 1.f / sum;
      bool msk = (k0 + kl) > (q0 + q);
#pragma unroll
      for (int h = 0; h < 16; h++)
        Ab[h * 1152 + base] = msk ? (short)0 : f2bf(t[h] * rs - 0.0625f);
    }
    __syncthreads();
    // ---- Y += A' @ V ----
#pragma unroll
    for (int hh = 0; hh < 2; hh++) {
      int h = h0 + hh;
#pragma unroll
      for (int kk = 0; kk < 2; kk++) {
        bf16x8 af = *(const bf16x8*)&Ab[(h * 16 + l15) * 72 + kk * 32 + quad * 8];
#pragma unroll
        for (int nt = 0; nt < 4; nt++) {
          bf16x8 vf = *(const bf16x8*)&Vt[((size_t)h * 64 + nt * 16 + l15) * 2048 +
                                          k0 + kk * 32 + quad * 8];
          yacc[hh][nt] = __builtin_amdgcn_mfma_f32_16x16x32_bf16(af, vf, yacc[hh][nt],
                                                                 0, 0, 0);
        }
      }
    }
    __syncthreads();
  }
  // store bf16 partial (zeros if this split had no groups)
  short* Y = Yp + (size_t)s * 2048 * 1024;
#pragma unroll
  for (int hh = 0; hh < 2; hh++) {
#pragma unroll
    for (int nt = 0; nt < 4; nt++) {
      int col = (h0 + hh) * 64 + nt * 16 + l15;
#pragma unroll
      for (int r = 0; r < 4; r++)
        Y[(size_t)(q0 + quad * 4 + r) * 1024 + col] = f2bf(yacc[hh][nt][r]);
    }
  }
}

// ---------- host ----------
extern "C" void kernel_launch(void* const* d_in, const int* in_sizes, int n_in,
                              void* d_out, int out_size, void* d_ws, size_t ws_size,
                              hipStream_t stream) {
  (void)in_sizes; (void)n_in; (void)out_size; (void)ws_size;
  const float* X  = (const float*)d_in[0];
  const float* Wq = (const float*)d_in[2];
  const float* Wk = (const float*)d_in[3];
  const float* Wv = (const float*)d_in[4];
  const float* Wo = (const float*)d_in[5];
  char* ws = (char*)d_ws;
  const size_t MB = 1024 * 1024;
  short* Xbf   = (short*)(ws + 0);        // 4 MB; reused as Ycbf after gemm1
  short* WcatT = (short*)(ws + 4 * MB);   // 6 MB [3072 n][1024 k]
  short* WoT   = (short*)(ws + 10 * MB);  // 2 MB [1024 n][1024 k]
  short* Qb    = (short*)(ws + 12 * MB);  // 4 MB [h][q][64]
  short* Kb    = (short*)(ws + 16 * MB);  // 4 MB [h][k][64]
  short* Vb    = (short*)(ws + 20 * MB);  // 4 MB [h][k][64]
  short* Vt    = (short*)(ws + 24 * MB);  // 4 MB [h][d][2048]
  short* Yp    = (short*)(ws + 28 * MB);  // 16 MB: 4 bf16 partials [2048][1024]
  float* Cvs   = (float*)(ws + 44 * MB);  // 4 KB
  short* Ycbf  = Xbf;                     // alias (Xbf dead after gemm1)
  float* out   = (float*)d_out;

  cast_b<<<dim3(2048), dim3(256), 0, stream>>>(X, Xbf);
  transW<<<dim3(32, 32, 4), dim3(256), 0, stream>>>(Wq, Wk, Wv, Wo, WcatT, WoT);
  gemm_kernel<1><<<dim3(16, 24), dim3(256), 0, stream>>>(Xbf, WcatT, 3072, 1024,
                                                         nullptr, Qb, Kb, Vb);
  transpose_v<<<dim3(32, 16), dim3(256), 0, stream>>>(Vb, Vt);
  vsum<<<dim3(64), dim3(256), 0, stream>>>(Vb, Cvs);
  attn_kernel<<<dim3(512), dim3(512), 0, stream>>>(Qb, Kb, Vt, Yp);
  cast_add4<<<dim3(2048), dim3(256), 0, stream>>>(Yp, Yp + 2048 * 1024,
                                                  Yp + 2 * 2048 * 1024,
                                                  Yp + 3 * 2048 * 1024, Cvs, Ycbf);
  gemm_kernel<0><<<dim3(16, 8), dim3(256), 0, stream>>>(Ycbf, WoT, 1024, 1024,
                                                        out, nullptr, nullptr, nullptr);
}